// Round 16
// baseline (31.012 us; speedup 1.0000x reference)
//
#include <hip/hip_runtime.h>

// Stand-alone self-attention block, fully fused.
// x:(8,64,128,128) f32 -> out same shape. G=8, Cg=8, 3x3 window, pad 1.
//
// R16 = R11 core (32x32 tile, 4 px/thread, SGPR weights, stride-38
// interleaved float2 kv LDS, b128 window reads, streaming no-max exp2
// softmax) with a 2-chunk pipelined block (4 channels), 2048 blocks:
//   conv A -> bar -> { conv B (regs) || attn A (buf0) } -> bar -> attn B
//  - x + halo loaded ONCE per 4 channels (VMEM + scattered-line FETCH halves)
//  - 1 barrier per chunk (R11 parity; R10's serial version had 2)
//  - double-buffered kv (41.3 KB): conv B writes buf1 while attn A reads buf0
//  - store A issued in phase 3 -> latency hidden under attn B
//  - plain __launch_bounds__(256): forcing retired (R6/R9/R13 collapses)

typedef float v2f __attribute__((ext_vector_type(2)));
typedef float v4f __attribute__((ext_vector_type(4)));

#define HH 128
#define WW 128
#define HW (HH * WW)
#define PTS 38         // LDS row stride in float2
#define LOG2E 1.44269504088896f

__device__ __forceinline__ float sload(float v) {
    return __uint_as_float(__builtin_amdgcn_readfirstlane(__float_as_uint(v)));
}

__global__ __launch_bounds__(256) void sab_fused(
    const float* __restrict__ x,
    const float* __restrict__ Wq,
    const float* __restrict__ Wk,
    const float* __restrict__ Wv,
    const float* __restrict__ h_emb,
    const float* __restrict__ w_emb,
    float* __restrict__ out)
{
    __shared__ v2f kv[2][2][34][PTS];   // [buf][cc][row][col] {k,v}  41.3 KB

    const int bid0 = blockIdx.x;
    const int work = (bid0 & 7) * 256 + (bid0 >> 3);   // bijective XCD swizzle
    const int c0   = (work & 1) << 2;          // chunk pair: channels c0..c0+3
    const int tile = (work >> 1) & 15;         // 4x4 tiles of 32x32
    const int bg   = work >> 5;                // b*8 + g
    const int g    = bg & 7;
    const int h0   = (tile >> 2) << 5;
    const int w0   = (tile & 3) << 5;
    const int tid  = threadIdx.x;
    const int ty   = tid >> 3;                 // 0..31
    const int x0   = (tid & 7) << 2;           // 0,4,..,28

    const float* xb = x + (size_t)bg * 8 * HW;
    const int ibase = (h0 + ty) * WW + (w0 + x0);

    // ---- chunk A weights (channels c0, c0+1) -> SGPRs ----
    float wkA[2][8], wvA[2][8], wqA[2][8], ebA[2][9];
    #pragma unroll
    for (int cc = 0; cc < 2; cc++) {
        const int c = c0 + cc;
        #pragma unroll
        for (int i = 0; i < 8; i++) {
            wkA[cc][i] = sload(Wk[g * 64 + c * 8 + i]);
            wvA[cc][i] = sload(Wv[g * 64 + c * 8 + i]);
            wqA[cc][i] = sload(Wq[g * 64 + c * 8 + i]);
        }
        #pragma unroll
        for (int p = 0; p < 9; p++)
            ebA[cc][p] = sload((c < 4) ? h_emb[(g * 4 + c) * 3 + p / 3]
                                       : w_emb[(g * 4 + c - 4) * 3 + p % 3]);
    }

    // ---- interior x: 4 px, 8 channels (dwordx4), once for both chunks ----
    v4f xi[8];
    #pragma unroll
    for (int i = 0; i < 8; i++)
        xi[i] = *reinterpret_cast<const v4f*>(xb + i * HW + ibase);

    // ---- halo x: 132 perimeter px on threads 0..131, once ----
    int hpy = 0, hpx = 0;
    const bool is_halo = tid < 132;
    if (is_halo) {
        if (tid < 34)       { hpy = 0;        hpx = tid; }
        else if (tid < 68)  { hpy = 33;       hpx = tid - 34; }
        else if (tid < 100) { hpy = tid - 67; hpx = 0; }     // rows 1..32
        else                { hpy = tid - 99; hpx = 33; }
    }
    const int hgh = h0 + hpy - 1, hgw = w0 + hpx - 1;
    const bool hok = is_halo & (hgh >= 0) & (hgh < HH) & (hgw >= 0) & (hgw < WW);
    const int hbase = hgh * WW + hgw;
    float hx[8];
    #pragma unroll
    for (int i = 0; i < 8; i++)
        hx[i] = hok ? xb[i * HW + hbase] : 0.0f;

    // ---- phase 1: conv A -> kv[0], qA ----
    float qA[2][4];
    {
        v4f kk0 = 0.f, vv0 = 0.f, qq0 = 0.f, kk1 = 0.f, vv1 = 0.f, qq1 = 0.f;
        #pragma unroll
        for (int i = 0; i < 8; i++) {
            const v4f xv = xi[i];
            kk0 += wkA[0][i] * xv;  vv0 += wvA[0][i] * xv;  qq0 += wqA[0][i] * xv;
            kk1 += wkA[1][i] * xv;  vv1 += wvA[1][i] * xv;  qq1 += wqA[1][i] * xv;
        }
        #pragma unroll
        for (int px = 0; px < 4; px++) {
            kv[0][0][ty + 1][x0 + 1 + px] = (v2f){kk0[px], vv0[px]};
            kv[0][1][ty + 1][x0 + 1 + px] = (v2f){kk1[px], vv1[px]};
        }
        #pragma unroll
        for (int px = 0; px < 4; px++) {
            qA[0][px] = qq0[px] * LOG2E;
            qA[1][px] = qq1[px] * LOG2E;
        }
        if (is_halo) {
            float hk0 = 0.f, hv0 = 0.f, hk1 = 0.f, hv1 = 0.f;
            #pragma unroll
            for (int i = 0; i < 8; i++) {
                hk0 = fmaf(wkA[0][i], hx[i], hk0);
                hv0 = fmaf(wvA[0][i], hx[i], hv0);
                hk1 = fmaf(wkA[1][i], hx[i], hk1);
                hv1 = fmaf(wvA[1][i], hx[i], hv1);
            }
            kv[0][0][hpy][hpx] = (v2f){hk0, hv0};
            kv[0][1][hpy][hpx] = (v2f){hk1, hv1};
        }
    }
    __syncthreads();

    // ---- phase 2: conv B -> kv[1] (from regs), then attn A (buf0) ----
    float qB[2][4];
    {
        // chunk B weights (channels c0+2, c0+3)
        float wkB[2][8], wvB[2][8], wqB[2][8];
        #pragma unroll
        for (int cc = 0; cc < 2; cc++) {
            const int c = c0 + 2 + cc;
            #pragma unroll
            for (int i = 0; i < 8; i++) {
                wkB[cc][i] = sload(Wk[g * 64 + c * 8 + i]);
                wvB[cc][i] = sload(Wv[g * 64 + c * 8 + i]);
                wqB[cc][i] = sload(Wq[g * 64 + c * 8 + i]);
            }
        }
        v4f kk0 = 0.f, vv0 = 0.f, qq0 = 0.f, kk1 = 0.f, vv1 = 0.f, qq1 = 0.f;
        #pragma unroll
        for (int i = 0; i < 8; i++) {
            const v4f xv = xi[i];
            kk0 += wkB[0][i] * xv;  vv0 += wvB[0][i] * xv;  qq0 += wqB[0][i] * xv;
            kk1 += wkB[1][i] * xv;  vv1 += wvB[1][i] * xv;  qq1 += wqB[1][i] * xv;
        }
        #pragma unroll
        for (int px = 0; px < 4; px++) {
            kv[1][0][ty + 1][x0 + 1 + px] = (v2f){kk0[px], vv0[px]};
            kv[1][1][ty + 1][x0 + 1 + px] = (v2f){kk1[px], vv1[px]};
        }
        #pragma unroll
        for (int px = 0; px < 4; px++) {
            qB[0][px] = qq0[px] * LOG2E;
            qB[1][px] = qq1[px] * LOG2E;
        }
        if (is_halo) {
            float hk0 = 0.f, hv0 = 0.f, hk1 = 0.f, hv1 = 0.f;
            #pragma unroll
            for (int i = 0; i < 8; i++) {
                hk0 = fmaf(wkB[0][i], hx[i], hk0);
                hv0 = fmaf(wvB[0][i], hx[i], hv0);
                hk1 = fmaf(wkB[1][i], hx[i], hk1);
                hv1 = fmaf(wvB[1][i], hx[i], hv1);
            }
            kv[1][0][hpy][hpx] = (v2f){hk0, hv0};
            kv[1][1][hpy][hpx] = (v2f){hk1, hv1};
        }

        // attn A (reads buf0; no conflict with buf1 writes above)
        float s[2][4] = {{0.f,0.f,0.f,0.f},{0.f,0.f,0.f,0.f}};
        float o[2][4] = {{0.f,0.f,0.f,0.f},{0.f,0.f,0.f,0.f}};
        #pragma unroll
        for (int dh = 0; dh < 3; dh++) {
            #pragma unroll
            for (int cc = 0; cc < 2; cc++) {
                const v2f* row = &kv[0][cc][ty + dh][x0];
                const v4f a  = *reinterpret_cast<const v4f*>(row);
                const v4f bq = *reinterpret_cast<const v4f*>(row + 2);
                const v4f cq = *reinterpret_cast<const v4f*>(row + 4);
                const float kw[6] = {a.x, a.z, bq.x, bq.z, cq.x, cq.z};
                const float vw[6] = {a.y, a.w, bq.y, bq.w, cq.y, cq.w};
                #pragma unroll
                for (int px = 0; px < 4; px++) {
                    const float ql = qA[cc][px];
                    #pragma unroll
                    for (int dw = 0; dw < 3; dw++) {
                        const float e = __builtin_amdgcn_exp2f(
                            ql * (kw[px + dw] + ebA[cc][dh * 3 + dw]));
                        s[cc][px] += e;
                        o[cc][px] = fmaf(e, vw[px + dw], o[cc][px]);
                    }
                }
            }
        }
        v4f r0, r1;
        #pragma unroll
        for (int px = 0; px < 4; px++) {
            r0[px] = o[0][px] * __builtin_amdgcn_rcpf(s[0][px]);
            r1[px] = o[1][px] * __builtin_amdgcn_rcpf(s[1][px]);
        }
        *reinterpret_cast<v4f*>(out + (size_t)(bg * 8 + c0 + 0) * HW + ibase) = r0;
        *reinterpret_cast<v4f*>(out + (size_t)(bg * 8 + c0 + 1) * HW + ibase) = r1;
    }
    __syncthreads();

    // ---- phase 3: attn B (buf1) ----
    {
        float ebB[2][9];
        #pragma unroll
        for (int cc = 0; cc < 2; cc++) {
            const int c = c0 + 2 + cc;
            #pragma unroll
            for (int p = 0; p < 9; p++)
                ebB[cc][p] = sload((c < 4) ? h_emb[(g * 4 + c) * 3 + p / 3]
                                           : w_emb[(g * 4 + c - 4) * 3 + p % 3]);
        }
        float s[2][4] = {{0.f,0.f,0.f,0.f},{0.f,0.f,0.f,0.f}};
        float o[2][4] = {{0.f,0.f,0.f,0.f},{0.f,0.f,0.f,0.f}};
        #pragma unroll
        for (int dh = 0; dh < 3; dh++) {
            #pragma unroll
            for (int cc = 0; cc < 2; cc++) {
                const v2f* row = &kv[1][cc][ty + dh][x0];
                const v4f a  = *reinterpret_cast<const v4f*>(row);
                const v4f bq = *reinterpret_cast<const v4f*>(row + 2);
                const v4f cq = *reinterpret_cast<const v4f*>(row + 4);
                const float kw[6] = {a.x, a.z, bq.x, bq.z, cq.x, cq.z};
                const float vw[6] = {a.y, a.w, bq.y, bq.w, cq.y, cq.w};
                #pragma unroll
                for (int px = 0; px < 4; px++) {
                    const float ql = qB[cc][px];
                    #pragma unroll
                    for (int dw = 0; dw < 3; dw++) {
                        const float e = __builtin_amdgcn_exp2f(
                            ql * (kw[px + dw] + ebB[cc][dh * 3 + dw]));
                        s[cc][px] += e;
                        o[cc][px] = fmaf(e, vw[px + dw], o[cc][px]);
                    }
                }
            }
        }
        v4f r0, r1;
        #pragma unroll
        for (int px = 0; px < 4; px++) {
            r0[px] = o[0][px] * __builtin_amdgcn_rcpf(s[0][px]);
            r1[px] = o[1][px] * __builtin_amdgcn_rcpf(s[1][px]);
        }
        *reinterpret_cast<v4f*>(out + (size_t)(bg * 8 + c0 + 2) * HW + ibase) = r0;
        *reinterpret_cast<v4f*>(out + (size_t)(bg * 8 + c0 + 3) * HW + ibase) = r1;
    }
}

extern "C" void kernel_launch(void* const* d_in, const int* in_sizes, int n_in,
                              void* d_out, int out_size, void* d_ws, size_t ws_size,
                              hipStream_t stream) {
    const float* x    = (const float*)d_in[0];
    const float* Wq   = (const float*)d_in[1];
    const float* Wk   = (const float*)d_in[2];
    const float* Wv   = (const float*)d_in[3];
    const float* h_e  = (const float*)d_in[4];
    const float* w_e  = (const float*)d_in[5];
    float* out = (float*)d_out;

    dim3 grid(8 * 8 * 16 * 2);   // (b,g) x 4x4 tiles x 2 chunk-pairs = 2048
    dim3 block(256);
    sab_fused<<<grid, block, 0, stream>>>(x, Wq, Wk, Wv, h_e, w_e, out);
}